// Round 1
// baseline (5534.888 us; speedup 1.0000x reference)
//
#include <hip/hip_runtime.h>
#include <hip/hip_fp16.h>

// Problem constants
#define TT 2048
#define II 1739
#define HN 256
#define H3 768

typedef _Float16 h2 __attribute__((ext_vector_type(2)));

__device__ __forceinline__ float fdot2(h2 a, h2 b, float c) {
#if defined(__has_builtin)
#if __has_builtin(__builtin_amdgcn_fdot2)
  return __builtin_amdgcn_fdot2(a, b, c, false);
#else
  return fmaf((float)a[0], (float)b[0], fmaf((float)a[1], (float)b[1], c));
#endif
#else
  return fmaf((float)a[0], (float)b[0], fmaf((float)a[1], (float)b[1], c));
#endif
}

template <int CTRL>
__device__ __forceinline__ float dpp_qperm(float v) {
  int r = __builtin_amdgcn_update_dpp(0, __builtin_bit_cast(int, v), CTRL, 0xF, 0xF, true);
  return __builtin_bit_cast(float, r);
}

// C[M,N] = A[M,K] @ B[N,K]^T + bias1[n] + (n < b2lim ? bias2[n] : 0)
// 64x64 tile, 256 threads, 4x4 micro-tile per thread.
__global__ __launch_bounds__(256) void gemm_abt(
    const float* __restrict__ A, int M, int K,
    const float* __restrict__ B, int N,
    const float* __restrict__ bias1, const float* __restrict__ bias2, int b2lim,
    float* __restrict__ C) {
  __shared__ float As[16][64];
  __shared__ float Bs[16][64];
  const int tid = threadIdx.x;
  const int m0 = blockIdx.y * 64, n0 = blockIdx.x * 64;
  const int lr = tid >> 2;        // 0..63  (row within tile for loads)
  const int lk = (tid & 3) * 4;   // 0,4,8,12
  const int cx = tid & 15, cy = tid >> 4;
  float acc[4][4] = {};

  for (int k0 = 0; k0 < K; k0 += 16) {
#pragma unroll
    for (int i = 0; i < 4; ++i) {
      int k = k0 + lk + i;
      As[lk + i][lr] = (k < K) ? A[(size_t)(m0 + lr) * K + k] : 0.f;
      int bn = n0 + lr;
      Bs[lk + i][lr] = (k < K && bn < N) ? B[(size_t)bn * K + k] : 0.f;
    }
    __syncthreads();
#pragma unroll
    for (int k = 0; k < 16; ++k) {
      float4 av = *(const float4*)&As[k][cy * 4];
      float4 bv = *(const float4*)&Bs[k][cx * 4];
      const float aa[4] = {av.x, av.y, av.z, av.w};
      const float bb[4] = {bv.x, bv.y, bv.z, bv.w};
#pragma unroll
      for (int i = 0; i < 4; ++i)
#pragma unroll
        for (int j = 0; j < 4; ++j) acc[i][j] = fmaf(aa[i], bb[j], acc[i][j]);
    }
    __syncthreads();
  }
#pragma unroll
  for (int i = 0; i < 4; ++i) {
    int m = m0 + cy * 4 + i;
#pragma unroll
    for (int j = 0; j < 4; ++j) {
      int n = n0 + cx * 4 + j;
      if (n < N) {
        float b = bias1 ? bias1[n] : 0.f;
        if (bias2 && n < b2lim) b += bias2[n];
        C[(size_t)m * N + n] = acc[i][j] + b;
      }
    }
  }
}

// Sequential GRU scan on a single CU (1 block, 512 threads = 8 waves).
// W_hh held as f16 pairs in registers (192 VGPR/thread).
// Thread layout: wave wv (0..7), lane; kc = lane&3 -> k-chunk [64*kc, 64*kc+64)
// row-group g = wv*16 + (lane>>2) in [0,128), rows r = 6g..6g+5.
// xp = x @ W_ih^T + b_ih + (b_hh for r,z rows only).  b_hh n-part applied in-gate.
__global__ __launch_bounds__(512) void gru_seq(
    const float* __restrict__ xp,      // [T, 768]
    const float* __restrict__ Whh,     // [768, 256]
    const float* __restrict__ bhh,     // [768]
    const float* __restrict__ h0,      // [256] or nullptr (zeros)
    float* __restrict__ hs_out,        // [T, 256] or nullptr
    float* __restrict__ hT_out) {      // [256] or nullptr
  __shared__ uint4 hbuf[32];   // h as 128 f16-pair dwords
  __shared__ float hh[H3];

  const int tid = threadIdx.x;
  const int lane = tid & 63;
  const int wv = tid >> 6;
  const int kc = lane & 3;
  const int g = wv * 16 + (lane >> 2);
  const int r0 = g * 6;

  // Load W_hh rows into registers as packed f16 pairs.
  h2 wreg[6][32];
#pragma unroll
  for (int i = 0; i < 6; ++i) {
    const float* wr = Whh + (size_t)(r0 + i) * HN + kc * 64;
#pragma unroll
    for (int p = 0; p < 32; ++p) {
      float2 f = *(const float2*)(wr + 2 * p);
      wreg[i][p] = h2{(_Float16)f.x, (_Float16)f.y};
    }
  }

  float hj = 0.f, bhn = 0.f;
  if (tid < HN) {
    hj = h0 ? h0[tid] : 0.f;
    bhn = bhh[2 * HN + tid];
  }
  if (tid < 128) {
    float a = h0 ? h0[2 * tid] : 0.f;
    float b = h0 ? h0[2 * tid + 1] : 0.f;
    ((h2*)hbuf)[tid] = h2{(_Float16)a, (_Float16)b};
  }
  __syncthreads();

  for (int t = 0; t < TT; ++t) {
    // Prefetch this step's x-projection (lands during the matvec).
    float xr = 0.f, xz = 0.f, xn = 0.f;
    if (tid < HN) {
      const float* xpt = xp + (size_t)t * H3 + tid;
      xr = xpt[0];
      xz = xpt[HN];
      xn = xpt[2 * HN];
    }

    // Matvec: 6 rows x 64 k per thread, f16 dot2 with fp32 accumulate.
    float acc[6] = {0.f, 0.f, 0.f, 0.f, 0.f, 0.f};
#pragma unroll
    for (int hf = 0; hf < 2; ++hf) {
      uint4 v0 = hbuf[kc * 8 + hf * 4 + 0];
      uint4 v1 = hbuf[kc * 8 + hf * 4 + 1];
      uint4 v2 = hbuf[kc * 8 + hf * 4 + 2];
      uint4 v3 = hbuf[kc * 8 + hf * 4 + 3];
      uint hw[16] = {v0.x, v0.y, v0.z, v0.w, v1.x, v1.y, v1.z, v1.w,
                     v2.x, v2.y, v2.z, v2.w, v3.x, v3.y, v3.z, v3.w};
#pragma unroll
      for (int i = 0; i < 6; ++i)
#pragma unroll
        for (int p = 0; p < 16; ++p)
          acc[i] = fdot2(wreg[i][hf * 16 + p], __builtin_bit_cast(h2, hw[p]), acc[i]);
    }

    // Reduce the 4 k-chunk partials within each quad (pure VALU via DPP).
#pragma unroll
    for (int i = 0; i < 6; ++i) {
      float v = acc[i];
      v += dpp_qperm<0xB1>(v);  // xor 1
      v += dpp_qperm<0x4E>(v);  // xor 2
      acc[i] = v;
    }
    if (kc == 0) {
      *(float2*)&hh[r0 + 0] = make_float2(acc[0], acc[1]);
      *(float2*)&hh[r0 + 2] = make_float2(acc[2], acc[3]);
      *(float2*)&hh[r0 + 4] = make_float2(acc[4], acc[5]);
    }
    __syncthreads();

    // Gates (threads 0..255, one per hidden unit).
    if (tid < HN) {
      float r = 1.f / (1.f + __expf(-(xr + hh[tid])));
      float z = 1.f / (1.f + __expf(-(xz + hh[HN + tid])));
      float nv = 2.f / (1.f + __expf(-2.f * (xn + r * (hh[2 * HN + tid] + bhn)))) - 1.f;
      hj = (1.f - z) * nv + z * hj;
      if (hs_out) hs_out[(size_t)t * HN + tid] = hj;
      ((_Float16*)hbuf)[tid] = (_Float16)hj;
    }
    __syncthreads();
  }
  if (hT_out && tid < HN) hT_out[tid] = hj;
}

extern "C" void kernel_launch(void* const* d_in, const int* in_sizes, int n_in,
                              void* d_out, int out_size, void* d_ws, size_t ws_size,
                              hipStream_t stream) {
  const float* x     = (const float*)d_in[0];   // [1, 2048, 1739]
  const float* Wih_e = (const float*)d_in[2];   // [768, 1739]
  const float* Whh_e = (const float*)d_in[3];   // [768, 256]
  const float* bih_e = (const float*)d_in[4];   // [768]
  const float* bhh_e = (const float*)d_in[5];   // [768]
  const float* Wih_d = (const float*)d_in[6];
  const float* Whh_d = (const float*)d_in[7];
  const float* bih_d = (const float*)d_in[8];
  const float* bhh_d = (const float*)d_in[9];
  const float* Wout  = (const float*)d_in[10];  // [1739, 256]
  const float* bout  = (const float*)d_in[11];  // [1739]
  float* out = (float*)d_out;                   // [2048, 1, 1739]

  float* ws = (float*)d_ws;
  float* xpe  = ws;                              // 2048*768
  float* xpd  = xpe + (size_t)TT * H3;           // 2048*768
  float* hs   = xpd + (size_t)TT * H3;           // 2048*256
  float* henc = hs + (size_t)TT * HN;            // 256

  dim3 blk(256);
  // x-projections (b_hh folded in for r,z rows; n rows get b_ih only)
  gemm_abt<<<dim3(12, 32), blk, 0, stream>>>(x, TT, II, Wih_e, H3, bih_e, bhh_e, 2 * HN, xpe);
  gemm_abt<<<dim3(12, 32), blk, 0, stream>>>(x, TT, II, Wih_d, H3, bih_d, bhh_d, 2 * HN, xpd);
  // encoder scan -> henc
  gru_seq<<<1, 512, 0, stream>>>(xpe, Whh_e, bhh_e, nullptr, nullptr, henc);
  // decoder scan -> hs
  gru_seq<<<1, 512, 0, stream>>>(xpd, Whh_d, bhh_d, henc, hs, nullptr);
  // output projection
  gemm_abt<<<dim3(28, 32), blk, 0, stream>>>(hs, TT, HN, Wout, II, bout, nullptr, 0, out);
}